// Round 1
// baseline (715.123 us; speedup 1.0000x reference)
//
#include <hip/hip_runtime.h>
#include <math.h>

// DetPostProcessor: B=512 rows; per row: top-300 of sigmoid(logits[230400]),
// then labels = idx%256, boxes = scale(cxcywh_to_xyxy(pred_boxes[idx/256])).
//
// Strategy (one block per row, 1024 threads):
//   Pass 1: global read, 16-bin nibble histogram of key top-4-bits (ballot-free,
//           per-thread nibble-packed counters -> registers -> wave shuffle reduce).
//           Pick coarse threshold T with count(key>=T) in [300, CAP1].
//           (generic loop refines 4 bits/pass for pathological distributions;
//            for N(0,1) data one pass suffices: threshold at x=2.0, ~5250 cands)
//   Pass 2: global read, compact key>=T into LDS buf1.
//   Phase 3: in-LDS 256-bin radix refine (bits [27:20], ...) down to <=1024.
//   Phase 4: bitonic sort 1024 of composite (key<<32)|~idx  (desc key, asc idx
//            == jax.lax.top_k tie semantics on the monotone key).
//   Epilogue: f64 sigmoid scores, labels, box gather + cxcywh->xyxy + scale.

#define NB 512
#define NQ 900
#define NC 256
#define NELEM (NQ*NC)      // 230400
#define NF4 (NELEM/4)      // 57600
#define NSEL 300
#define NTHREADS 1024
#define CAP1 6144          // 48 KB as uint2
#define CAP2 1024          // 8 KB as uint2
#define SORT_N 1024

__device__ __forceinline__ unsigned keyOf(float f) {
    unsigned u = __float_as_uint(f);
    return u ^ ((unsigned)((int)u >> 31) | 0x80000000u);
}
__device__ __forceinline__ float keyToFloat(unsigned k) {
    unsigned u = (k & 0x80000000u) ? (k ^ 0x80000000u) : ~k;
    return __uint_as_float(u);
}

__global__ __launch_bounds__(NTHREADS) void detpost_kernel(
    const float* __restrict__ logits, const float* __restrict__ boxes,
    const float* __restrict__ tsizes, float* __restrict__ out)
{
    __shared__ uint2 buf1[CAP1];
    __shared__ uint2 buf2[CAP2];
    __shared__ unsigned hist[256];
    __shared__ unsigned sAbove, sCnt, sT, sCand, sDone;

    const int tid  = threadIdx.x;
    const int lane = tid & 63;
    const int row  = blockIdx.x;
    const float4* row4 = (const float4*)(logits + (size_t)row * NELEM);

    // ---------- Global select: find T with count(key>=T) in [NSEL, CAP1] ----------
    unsigned P = 0, pos = 28, T = 0, cand = 0;
    while (true) {
        if (tid < 16) hist[tid] = 0;
        if (tid == 16 % NTHREADS + 16) {}   // no-op
        if (tid == 17) sAbove = 0;
        __syncthreads();

        unsigned c[16];
        #pragma unroll
        for (int n = 0; n < 16; ++n) c[n] = 0;
        unsigned cAb = 0;
        const unsigned long long upper = (unsigned long long)P + (16ULL << pos);
        unsigned long long acc = 0; int pend = 0;

        for (unsigned i = tid; i < NF4; i += NTHREADS) {
            float4 v = row4[i];
            #pragma unroll
            for (int c4 = 0; c4 < 4; ++c4) {
                float f = (c4 == 0) ? v.x : (c4 == 1) ? v.y : (c4 == 2) ? v.z : v.w;
                unsigned k = keyOf(f);
                if ((unsigned long long)k >= upper) cAb++;
                else if (k >= P) acc += 1ULL << (((k >> pos) & 0xFu) << 2);
            }
            if (++pend == 3) {   // flush nibbles (max 12 < 16 per nibble)
                pend = 0;
                #pragma unroll
                for (int n = 0; n < 16; ++n) c[n] += (unsigned)(acc >> (4 * n)) & 0xFu;
                acc = 0;
            }
        }
        #pragma unroll
        for (int n = 0; n < 16; ++n) c[n] += (unsigned)(acc >> (4 * n)) & 0xFu;

        // wave reduce, one atomic per wave per non-zero bin
        #pragma unroll
        for (int n = 0; n < 16; ++n) {
            unsigned v = c[n];
            for (int off = 32; off; off >>= 1) v += __shfl_down(v, off, 64);
            if (lane == 0 && v) atomicAdd(&hist[n], v);
        }
        {
            unsigned v = cAb;
            for (int off = 32; off; off >>= 1) v += __shfl_down(v, off, 64);
            if (lane == 0 && v) atomicAdd(&sAbove, v);
        }
        __syncthreads();

        if (tid == 0) {
            unsigned run = sAbove; int b = 0;
            for (int n = 15; n >= 0; --n) {
                run += hist[n];
                if (run >= NSEL) { b = n; break; }
            }
            sT = P | ((unsigned)b << pos);
            sCand = run;
            sDone = (run <= CAP1 || pos == 0) ? 1u : 0u;
        }
        __syncthreads();
        T = sT; cand = sCand;
        unsigned done = sDone;
        __syncthreads();
        if (done) break;
        P = T; pos -= 4;   // pathological path: another full global pass, 4 more bits
    }

    // ---------- Pass 2: compact key >= T into buf1 ----------
    if (tid == 0) sCnt = 0;
    __syncthreads();
    for (unsigned i = tid; i < NF4; i += NTHREADS) {
        float4 v = row4[i];
        #pragma unroll
        for (int c4 = 0; c4 < 4; ++c4) {
            float f = (c4 == 0) ? v.x : (c4 == 1) ? v.y : (c4 == 2) ? v.z : v.w;
            unsigned k = keyOf(f);
            if (k >= T) {
                unsigned p2 = atomicAdd(&sCnt, 1u);
                if (p2 < CAP1) buf1[p2] = make_uint2(k, i * 4u + (unsigned)c4);
            }
        }
    }
    __syncthreads();
    unsigned cnt = min(sCnt, (unsigned)CAP1);
    (void)cand;

    // ---------- Phase 3: in-LDS radix refine to <= CAP2 ----------
    uint2* src = buf1; uint2* dst = buf2;
    unsigned dstCap = CAP2;
    int p = (int)pos - 8;                  // pos=28 -> levels at 20, 12, 4
    while (cnt > CAP2 && p >= 0) {
        if (tid < 256) hist[tid] = 0;
        if (tid == 0) { sAbove = 0; sCnt = 0; }
        __syncthreads();

        const unsigned Pm = T & (0xFFFFFFFFu << (p + 8));
        const unsigned long long up = (unsigned long long)Pm + (1ULL << (p + 8));
        for (unsigned i = tid; i < cnt; i += NTHREADS) {
            unsigned k = src[i].x;
            if ((unsigned long long)k >= up) atomicAdd(&sAbove, 1u);
            else atomicAdd(&hist[(k >> p) & 0xFFu], 1u);
        }
        __syncthreads();

        if (tid == 0) {
            unsigned run = sAbove; int b = 0;
            for (int n = 255; n >= 0; --n) {
                run += hist[n];
                if (run >= NSEL) { b = n; break; }
            }
            sT = Pm | ((unsigned)b << p);
            sCand = run;
        }
        __syncthreads();
        const unsigned Tn = sT;
        const unsigned newCnt = min(sCand, dstCap);
        for (unsigned i = tid; i < cnt; i += NTHREADS) {
            uint2 e = src[i];
            if (e.x >= Tn) {
                unsigned q = atomicAdd(&sCnt, 1u);
                if (q < dstCap) dst[q] = e;
            }
        }
        __syncthreads();
        T = Tn; cnt = newCnt;
        uint2* t = src; src = dst; dst = t;
        dstCap = (dst == buf1) ? (unsigned)CAP1 : (unsigned)CAP2;
        p -= 8;
    }
    if (cnt > CAP2) cnt = CAP2;            // pathological clamp, never for this input

    // ---------- Phase 4: bitonic sort (desc) of composite keys ----------
    // zbuf aliases buf1; safe: slot i read+written only by the thread owning i,
    // and when src==buf2, buf1 is dead.
    unsigned long long* zb = (unsigned long long*)buf1;
    {
        unsigned i = tid;  // SORT_N == NTHREADS
        unsigned long long z = 0;
        if (i < cnt) {
            uint2 e = src[i];
            z = ((unsigned long long)e.x << 32) | (unsigned)(~e.y);
        }
        zb[i] = z;
    }
    __syncthreads();
    for (unsigned kk = 2; kk <= SORT_N; kk <<= 1) {
        for (unsigned j = kk >> 1; j > 0; j >>= 1) {
            unsigned i = tid, ixj = i ^ j;
            if (ixj > i) {
                unsigned long long a = zb[i], bz = zb[ixj];
                bool sw = ((i & kk) == 0) ? (a < bz) : (a > bz);
                if (sw) { zb[i] = bz; zb[ixj] = a; }
            }
            __syncthreads();
        }
    }

    // ---------- Epilogue ----------
    if (tid < NSEL) {
        unsigned long long z = zb[tid];
        unsigned k   = (unsigned)(z >> 32);
        unsigned idx = ~(unsigned)z;
        float f = keyToFloat(k);
        double pd = 1.0 / (1.0 + exp(-(double)f));   // f64 sigmoid: <=1ulp vs np ref
        unsigned label = idx & (NC - 1);
        unsigned q = idx >> 8;                       // NC = 256
        float4 bx = ((const float4*)boxes)[(size_t)row * NQ + q];
        float imh = tsizes[row * 2 + 0];
        float imw = tsizes[row * 2 + 1];
        float x0 = (bx.x - bx.z * 0.5f) * imw;
        float y0 = (bx.y - bx.w * 0.5f) * imh;
        float x1 = (bx.x + bx.z * 0.5f) * imw;
        float y1 = (bx.y + bx.w * 0.5f) * imh;
        out[(size_t)row * NSEL + tid] = (float)pd;
        out[(size_t)NB * NSEL + (size_t)row * NSEL + tid] = (float)label;
        float* ob = out + (size_t)2 * NB * NSEL + ((size_t)row * NSEL + tid) * 4;
        ob[0] = x0; ob[1] = y0; ob[2] = x1; ob[3] = y1;
    }
}

extern "C" void kernel_launch(void* const* d_in, const int* in_sizes, int n_in,
                              void* d_out, int out_size, void* d_ws, size_t ws_size,
                              hipStream_t stream) {
    const float* logits = (const float*)d_in[0];   // (512, 900, 256) fp32
    const float* boxes  = (const float*)d_in[1];   // (512, 900, 4)  fp32
    const float* tsz    = (const float*)d_in[2];   // (512, 2)       fp32
    float* out = (float*)d_out;                    // scores|labels|boxes concat
    detpost_kernel<<<NB, NTHREADS, 0, stream>>>(logits, boxes, tsz, out);
}

// Round 2
// 690.365 us; speedup vs baseline: 1.0359x; 1.0359x over previous
//
#include <hip/hip_runtime.h>
#include <math.h>

// DetPostProcessor: B=512 rows; per row: top-300 of sigmoid(logits[230400]),
// labels = idx%256, boxes = scale(cxcywh_to_xyxy(pred_boxes[idx/256])).
//
// One block per row, 1024 threads. Phases:
//   A: stream row (4 independent float4 loads/thread/iter), 8192-bin LDS-atomic
//      histogram of top-13 key bits. Parallel suffix-scan picks threshold T =
//      finest bin boundary with count(key>=T) >= 300 (count <= CAP=2048 for any
//      sane distribution; generic window-refine loop retained as fallback).
//   B: stream row again (pass-2 largely L3-resident), compact key>=T directly
//      as sort composite (key<<32)|~idx into LDS.
//   C: bitonic sort 1024 (or 2048) desc -> exact top-300 with lax.top_k tie
//      semantics (equal key -> lowest index first).
//   D: epilogue: f64 sigmoid scores, labels, box gather + cxcywh->xyxy + scale.

#define NB 512
#define NQ 900
#define NC 256
#define NELEM (NQ*NC)      // 230400
#define NF4 (NELEM/4)      // 57600 = 14*4096 + 256
#define NSEL 300
#define NT 1024
#define HBINS 8192
#define CAP 2048

typedef unsigned long long ull;

__device__ __forceinline__ unsigned keyOf(float f) {
    unsigned u = __float_as_uint(f);
    return u ^ ((unsigned)((int)u >> 31) | 0x80000000u);
}
__device__ __forceinline__ float keyToFloat(unsigned k) {
    unsigned u = (k & 0x80000000u) ? (k ^ 0x80000000u) : ~k;
    return __uint_as_float(u);
}

__global__ __launch_bounds__(NT) void detpost_kernel(
    const float* __restrict__ logits, const float* __restrict__ boxes,
    const float* __restrict__ tsizes, float* __restrict__ out)
{
    __shared__ unsigned hist[HBINS];          // 32 KB
    __shared__ ull zb[CAP];                   // 16 KB (candidates == sort buffer)
    __shared__ unsigned suf[NT];              // 4 KB
    __shared__ unsigned sT, sCand, sAbove, sDone, sCnt;

    const int tid = threadIdx.x;
    const int row = blockIdx.x;
    const float4* __restrict__ r4 = (const float4*)(logits + (size_t)row * NELEM);

    // ---------------- Phase A: histogram + threshold ----------------
    unsigned W0 = 0;      // window base (key space)
    unsigned sh = 19;     // bin = (key - W0) >> sh ; window width = 2^(sh+13)
    unsigned above = 0;   // count of keys >= window top
    unsigned T, cand;

    while (true) {
        for (int i = tid; i < HBINS; i += NT) hist[i] = 0;
        __syncthreads();

        unsigned i0 = tid;
        #pragma unroll 1
        for (int it = 0; it < 14; ++it, i0 += 4096) {
            float4 a = r4[i0];
            float4 b = r4[i0 + 1024];
            float4 c = r4[i0 + 2048];
            float4 d = r4[i0 + 3072];
            #define PH(f) { unsigned k = keyOf(f); unsigned bin = (k - W0) >> sh; \
                            if (bin < HBINS) atomicAdd(&hist[bin], 1u); }
            PH(a.x) PH(a.y) PH(a.z) PH(a.w)
            PH(b.x) PH(b.y) PH(b.z) PH(b.w)
            PH(c.x) PH(c.y) PH(c.z) PH(c.w)
            PH(d.x) PH(d.y) PH(d.z) PH(d.w)
        }
        if (tid < 256) {
            float4 a = r4[57344 + tid];
            PH(a.x) PH(a.y) PH(a.z) PH(a.w)
        }
        __syncthreads();

        // coarse partial: thread t owns bins [8t, 8t+8)
        unsigned local = 0;
        #pragma unroll
        for (int j = 0; j < 8; ++j) local += hist[tid * 8 + j];
        suf[tid] = local;
        __syncthreads();
        // inclusive suffix scan over 1024 partials
        for (int off = 1; off < NT; off <<= 1) {
            unsigned v = suf[tid] + ((tid + off < NT) ? suf[tid + off] : 0u);
            __syncthreads();
            suf[tid] = v;
            __syncthreads();
        }
        unsigned mySuf = suf[tid];
        unsigned nxt = (tid < NT - 1) ? suf[tid + 1] : 0u;
        if (above + mySuf >= NSEL && above + nxt < NSEL) {
            // crossing chunk: walk its 8 bins from the top
            unsigned run = above + nxt;
            for (int j = 7; j >= 0; --j) {
                unsigned h = hist[tid * 8 + j];
                run += h;
                if (run >= NSEL) {
                    sT = W0 + ((unsigned)(tid * 8 + j) << sh);
                    sCand = run;
                    sAbove = run - h;            // count strictly above chosen bin
                    sDone = (run <= CAP || sh == 0) ? 1u : 0u;
                    break;
                }
            }
        }
        __syncthreads();
        T = sT; cand = sCand;
        if (sDone) break;
        // pathological fallback: refine inside the chosen bin (never for N(0,1))
        above = sAbove;
        W0 = T;
        sh = (sh >= 13) ? (sh - 13) : 0u;
        __syncthreads();
    }
    (void)cand;

    // ---------------- Phase B: compact key >= T as composites ----------------
    if (tid == 0) sCnt = 0;
    __syncthreads();
    {
        unsigned i0 = tid;
        #pragma unroll 1
        for (int it = 0; it < 14; ++it, i0 += 4096) {
            float4 a = r4[i0];
            float4 b = r4[i0 + 1024];
            float4 c = r4[i0 + 2048];
            float4 d = r4[i0 + 3072];
            #define PC(f, ei) { unsigned k = keyOf(f); if (k >= T) { \
                unsigned p = atomicAdd(&sCnt, 1u); \
                if (p < CAP) zb[p] = ((ull)k << 32) | (unsigned)~(unsigned)(ei); } }
            PC(a.x, i0*4+0)          PC(a.y, i0*4+1)          PC(a.z, i0*4+2)          PC(a.w, i0*4+3)
            PC(b.x, (i0+1024)*4+0)   PC(b.y, (i0+1024)*4+1)   PC(b.z, (i0+1024)*4+2)   PC(b.w, (i0+1024)*4+3)
            PC(c.x, (i0+2048)*4+0)   PC(c.y, (i0+2048)*4+1)   PC(c.z, (i0+2048)*4+2)   PC(c.w, (i0+2048)*4+3)
            PC(d.x, (i0+3072)*4+0)   PC(d.y, (i0+3072)*4+1)   PC(d.z, (i0+3072)*4+2)   PC(d.w, (i0+3072)*4+3)
        }
        if (tid < 256) {
            float4 a = r4[57344 + tid];
            unsigned e0 = (57344 + tid) * 4;
            PC(a.x, e0+0) PC(a.y, e0+1) PC(a.z, e0+2) PC(a.w, e0+3)
        }
    }
    __syncthreads();
    unsigned cnt = min(sCnt, (unsigned)CAP);

    // ---------------- Phase C: bitonic sort (desc) ----------------
    unsigned nSort = (cnt <= 1024u) ? 1024u : (unsigned)CAP;
    for (unsigned i = tid; i < nSort; i += NT)
        if (i >= cnt) zb[i] = 0ULL;   // pads sort to the bottom
    __syncthreads();
    for (unsigned kk = 2; kk <= nSort; kk <<= 1) {
        for (unsigned j = kk >> 1; j > 0; j >>= 1) {
            for (unsigned i = tid; i < nSort; i += NT) {
                unsigned ixj = i ^ j;
                if (ixj > i) {
                    ull A = zb[i], B = zb[ixj];
                    bool sw = ((i & kk) == 0) ? (A < B) : (A > B);
                    if (sw) { zb[i] = B; zb[ixj] = A; }
                }
            }
            __syncthreads();
        }
    }

    // ---------------- Phase D: epilogue ----------------
    if (tid < NSEL) {
        ull z = zb[tid];
        unsigned k   = (unsigned)(z >> 32);
        unsigned idx = ~(unsigned)z;
        float f = keyToFloat(k);
        double pd = 1.0 / (1.0 + exp(-(double)f));   // f64 sigmoid, matches np ref
        unsigned label = idx & (NC - 1);
        unsigned q = idx >> 8;                       // NC == 256
        float4 bx = ((const float4*)boxes)[(size_t)row * NQ + q];
        float imh = tsizes[row * 2 + 0];
        float imw = tsizes[row * 2 + 1];
        float x0 = (bx.x - bx.z * 0.5f) * imw;
        float y0 = (bx.y - bx.w * 0.5f) * imh;
        float x1 = (bx.x + bx.z * 0.5f) * imw;
        float y1 = (bx.y + bx.w * 0.5f) * imh;
        out[(size_t)row * NSEL + tid] = (float)pd;
        out[(size_t)NB * NSEL + (size_t)row * NSEL + tid] = (float)label;
        float* ob = out + (size_t)2 * NB * NSEL + ((size_t)row * NSEL + tid) * 4;
        ob[0] = x0; ob[1] = y0; ob[2] = x1; ob[3] = y1;
    }
}

extern "C" void kernel_launch(void* const* d_in, const int* in_sizes, int n_in,
                              void* d_out, int out_size, void* d_ws, size_t ws_size,
                              hipStream_t stream) {
    const float* logits = (const float*)d_in[0];   // (512, 900, 256) fp32
    const float* boxes  = (const float*)d_in[1];   // (512, 900, 4)  fp32
    const float* tsz    = (const float*)d_in[2];   // (512, 2)       fp32
    float* out = (float*)d_out;                    // scores|labels|boxes concat
    detpost_kernel<<<NB, NT, 0, stream>>>(logits, boxes, tsz, out);
}

// Round 3
// 654.000 us; speedup vs baseline: 1.0935x; 1.0556x over previous
//
#include <hip/hip_runtime.h>
#include <math.h>

// DetPostProcessor: B=512 rows; per row: top-300 of sigmoid(logits[230400]),
// labels = idx%256, boxes = scale(cxcywh_to_xyxy(pred_boxes[idx/256])).
//
// Single-pass design (one block per row, 1024 threads):
//   Stream: each thread keeps a register-resident top-6 of composites
//           (key<<32)|~idx over its 225 strided elements. No LDS, no barriers,
//           no atomics in the loop -> pure memory-bound (472 MB once).
//   Select: 4096-bin LDS histogram of the 6144 register-resident candidates
//           (multi-level window refine), threshold T with count(>=T)>=300.
//   Compact + bitonic sort (desc composite) -> exact top-300, lax.top_k tie
//           semantics (equal key -> lowest index first).
//   Guard:  thread may have dropped a true top-300 element only if its 6th-best
//           key > Khat (=300th key). Flag -> rare exact global re-read pass
//           with threshold Khat (P < 0.1% per row).
//   Epilogue: f64 sigmoid scores, labels, box gather + cxcywh->xyxy + scale.

#define NB 512
#define NQ 900
#define NC 256
#define NELEM (NQ*NC)      // 230400
#define NF4 (NELEM/4)      // 57600 = 14*4096 + 256
#define NSEL 300
#define NT 1024
#define HB 4096
#define CAP 2048

typedef unsigned long long ull;

__device__ __forceinline__ unsigned keyOf(float f) {
    unsigned u = __float_as_uint(f);
    return u ^ ((unsigned)((int)u >> 31) | 0x80000000u);
}
__device__ __forceinline__ float keyToFloat(unsigned k) {
    unsigned u = (k & 0x80000000u) ? (k ^ 0x80000000u) : ~k;
    return __uint_as_float(u);
}

__device__ __forceinline__ void bitonicSortDesc(ull* zb, unsigned nSort, int tid) {
    for (unsigned kk = 2; kk <= nSort; kk <<= 1) {
        for (unsigned j = kk >> 1; j > 0; j >>= 1) {
            for (unsigned i = tid; i < nSort; i += NT) {
                unsigned ixj = i ^ j;
                if (ixj > i) {
                    ull A = zb[i], B = zb[ixj];
                    bool sw = ((i & kk) == 0) ? (A < B) : (A > B);
                    if (sw) { zb[i] = B; zb[ixj] = A; }
                }
            }
            __syncthreads();
        }
    }
}

__global__ __launch_bounds__(NT) void detpost_kernel(
    const float* __restrict__ logits, const float* __restrict__ boxes,
    const float* __restrict__ tsizes, float* __restrict__ out)
{
    __shared__ unsigned hist[HB];          // 16 KB
    __shared__ ull zb[CAP];                // 16 KB
    __shared__ unsigned suf[NT];           // 4 KB
    __shared__ unsigned sT, sCand, sAbove, sCnt, sFlag;

    const int tid = threadIdx.x;
    const int row = blockIdx.x;
    const float4* __restrict__ r4 = (const float4*)(logits + (size_t)row * NELEM);

    // ---------------- Stream: per-thread top-6 (registers only) ----------------
    ull z0 = 0, z1 = 0, z2 = 0, z3 = 0, z4 = 0, z5 = 0;
    unsigned key5 = 0;   // key of z5 (running 6th-best); 0 = empty sentinel

    #define INS(f, ei) { unsigned k = keyOf(f); if (k > key5) { \
        ull z = ((ull)k << 32) | (unsigned)~(unsigned)(ei); \
        if (z > z0)      { z5=z4; z4=z3; z3=z2; z2=z1; z1=z0; z0=z; } \
        else if (z > z1) { z5=z4; z4=z3; z3=z2; z2=z1; z1=z; } \
        else if (z > z2) { z5=z4; z4=z3; z3=z2; z2=z; } \
        else if (z > z3) { z5=z4; z4=z3; z3=z; } \
        else if (z > z4) { z5=z4; z4=z; } \
        else             { z5=z; } \
        key5 = (unsigned)(z5 >> 32); } }

    {
        unsigned i0 = tid;
        #pragma unroll 1
        for (int it = 0; it < 14; ++it, i0 += 4096) {
            float4 a = r4[i0];
            float4 b = r4[i0 + 1024];
            float4 c = r4[i0 + 2048];
            float4 d = r4[i0 + 3072];
            unsigned e = i0 * 4u;
            INS(a.x, e)         INS(a.y, e+1)       INS(a.z, e+2)       INS(a.w, e+3)
            INS(b.x, e+4096)    INS(b.y, e+4097)    INS(b.z, e+4098)    INS(b.w, e+4099)
            INS(c.x, e+8192)    INS(c.y, e+8193)    INS(c.z, e+8194)    INS(c.w, e+8195)
            INS(d.x, e+12288)   INS(d.y, e+12289)   INS(d.z, e+12290)   INS(d.w, e+12291)
        }
        if (tid < 256) {
            float4 a = r4[57344 + tid];
            unsigned e = (57344u + tid) * 4u;
            INS(a.x, e) INS(a.y, e+1) INS(a.z, e+2) INS(a.w, e+3)
        }
    }

    // ---------------- Select T among the 6144 union candidates ----------------
    unsigned T, cand;
    unsigned W0 = 0; int sh = 20; int wlog2 = 32;
    while (true) {
        for (int i = tid; i < HB; i += NT) hist[i] = 0;
        if (tid == 0) sAbove = 0;
        __syncthreads();

        const ull wtop = (wlog2 >= 32) ? (1ULL << 32) : ((ull)W0 + (1ULL << wlog2));
        #define HZ(zz) { unsigned k = (unsigned)((zz) >> 32); if (k >= W0) { \
            if ((ull)k < wtop) atomicAdd(&hist[(k - W0) >> sh], 1u); \
            else atomicAdd(&sAbove, 1u); } }
        HZ(z0) HZ(z1) HZ(z2) HZ(z3) HZ(z4) HZ(z5)
        #undef HZ
        __syncthreads();

        unsigned local = 0;
        #pragma unroll
        for (int j = 0; j < 4; ++j) local += hist[tid * 4 + j];
        suf[tid] = local;
        __syncthreads();
        for (int off = 1; off < NT; off <<= 1) {   // inclusive suffix scan
            unsigned v = suf[tid] + ((tid + off < NT) ? suf[tid + off] : 0u);
            __syncthreads();
            suf[tid] = v;
            __syncthreads();
        }
        const unsigned above = sAbove;
        const unsigned mySuf = suf[tid];
        const unsigned nxt = (tid < NT - 1) ? suf[tid + 1] : 0u;
        if (above + mySuf >= NSEL && above + nxt < NSEL) {   // exactly one thread
            unsigned run = above + nxt;
            for (int j = 3; j >= 0; --j) {
                run += hist[tid * 4 + j];
                if (run >= NSEL) {
                    sT = W0 + ((unsigned)(tid * 4 + j) << sh);
                    sCand = run;
                    break;
                }
            }
        }
        __syncthreads();
        T = sT; cand = sCand;
        if (cand <= 512 || sh == 0) break;
        W0 = T; wlog2 = sh; sh = (sh > 12) ? (sh - 12) : 0;   // 20 -> 8 -> 0
    }

    // ---------------- Compact union >= T, sort ----------------
    if (tid == 0) { sCnt = 0; sFlag = 0; }
    __syncthreads();
    #define APP(zz) { if ((unsigned)((zz) >> 32) >= T) { \
        unsigned p = atomicAdd(&sCnt, 1u); if (p < CAP) zb[p] = (zz); } }
    APP(z0) APP(z1) APP(z2) APP(z3) APP(z4) APP(z5)
    #undef APP
    __syncthreads();
    unsigned cnt = min(sCnt, (unsigned)CAP);
    unsigned nSort = (cnt <= 512u) ? 512u : (cnt <= 1024u ? 1024u : (unsigned)CAP);
    for (unsigned i = tid; i < nSort; i += NT) if (i >= cnt) zb[i] = 0ULL;
    __syncthreads();
    bitonicSortDesc(zb, nSort, tid);

    // ---------------- Validity guard (rare exact fallback) ----------------
    const unsigned Khat = (unsigned)(zb[NSEL - 1] >> 32);
    if (key5 > Khat) sFlag = 1u;   // this thread may have dropped a >=Khat elem
    __syncthreads();
    if (sFlag) {
        if (tid == 0) sCnt = 0;
        __syncthreads();
        #define PC(f, ei) { unsigned k = keyOf(f); if (k >= Khat) { \
            unsigned p = atomicAdd(&sCnt, 1u); \
            if (p < CAP) zb[p] = ((ull)k << 32) | (unsigned)~(unsigned)(ei); } }
        unsigned i0 = tid;
        #pragma unroll 1
        for (int it = 0; it < 14; ++it, i0 += 4096) {
            float4 a = r4[i0];
            float4 b = r4[i0 + 1024];
            float4 c = r4[i0 + 2048];
            float4 d = r4[i0 + 3072];
            unsigned e = i0 * 4u;
            PC(a.x, e)         PC(a.y, e+1)       PC(a.z, e+2)       PC(a.w, e+3)
            PC(b.x, e+4096)    PC(b.y, e+4097)    PC(b.z, e+4098)    PC(b.w, e+4099)
            PC(c.x, e+8192)    PC(c.y, e+8193)    PC(c.z, e+8194)    PC(c.w, e+8195)
            PC(d.x, e+12288)   PC(d.y, e+12289)   PC(d.z, e+12290)   PC(d.w, e+12291)
        }
        if (tid < 256) {
            float4 a = r4[57344 + tid];
            unsigned e = (57344u + tid) * 4u;
            PC(a.x, e) PC(a.y, e+1) PC(a.z, e+2) PC(a.w, e+3)
        }
        #undef PC
        __syncthreads();
        cnt = min(sCnt, (unsigned)CAP);
        nSort = (cnt <= 512u) ? 512u : (cnt <= 1024u ? 1024u : (unsigned)CAP);
        for (unsigned i = tid; i < nSort; i += NT) if (i >= cnt) zb[i] = 0ULL;
        __syncthreads();
        bitonicSortDesc(zb, nSort, tid);
    }

    // ---------------- Epilogue ----------------
    if (tid < NSEL) {
        ull z = zb[tid];
        unsigned k   = (unsigned)(z >> 32);
        unsigned idx = ~(unsigned)z;
        float f = keyToFloat(k);
        double pd = 1.0 / (1.0 + exp(-(double)f));   // f64 sigmoid, matches np ref
        unsigned label = idx & (NC - 1);
        unsigned q = idx >> 8;                       // NC == 256
        float4 bx = ((const float4*)boxes)[(size_t)row * NQ + q];
        float imh = tsizes[row * 2 + 0];
        float imw = tsizes[row * 2 + 1];
        float x0 = (bx.x - bx.z * 0.5f) * imw;
        float y0 = (bx.y - bx.w * 0.5f) * imh;
        float x1 = (bx.x + bx.z * 0.5f) * imw;
        float y1 = (bx.y + bx.w * 0.5f) * imh;
        out[(size_t)row * NSEL + tid] = (float)pd;
        out[(size_t)NB * NSEL + (size_t)row * NSEL + tid] = (float)label;
        float4* ob = (float4*)(out + (size_t)2 * NB * NSEL + ((size_t)row * NSEL + tid) * 4);
        *ob = make_float4(x0, y0, x1, y1);
    }
}

extern "C" void kernel_launch(void* const* d_in, const int* in_sizes, int n_in,
                              void* d_out, int out_size, void* d_ws, size_t ws_size,
                              hipStream_t stream) {
    const float* logits = (const float*)d_in[0];   // (512, 900, 256) fp32
    const float* boxes  = (const float*)d_in[1];   // (512, 900, 4)  fp32
    const float* tsz    = (const float*)d_in[2];   // (512, 2)       fp32
    float* out = (float*)d_out;                    // scores|labels|boxes concat
    detpost_kernel<<<NB, NT, 0, stream>>>(logits, boxes, tsz, out);
}